// Round 1
// baseline (534.812 us; speedup 1.0000x reference)
//
#include <hip/hip_runtime.h>
#include <hip/hip_bf16.h>
#include <stdint.h>

#define HCH 256
#define GEO 13
#define DEPTH 3
#define EPSBN 1e-5f

typedef __attribute__((ext_vector_type(8))) short short8;
typedef __attribute__((ext_vector_type(4))) float floatx4;

// fp32 -> bf16 RNE (inputs are finite; no NaN handling needed)
__device__ __forceinline__ short f2bs(float f) {
    unsigned u = __float_as_uint(f);
    unsigned r = (u + 0x7fffu + ((u >> 16) & 1u)) >> 16;
    return (short)r;
}

// ---------------- k_zero: zero output + branch counters ----------------
__global__ void k_zero(float4* out4, int n4, int* cnt) {
    int i = blockIdx.x * blockDim.x + threadIdx.x;
    if (i < n4) out4[i] = make_float4(0.f, 0.f, 0.f, 0.f);
    if (blockIdx.x == 0 && threadIdx.x < 4) cnt[threadIdx.x] = 0;
}

// ---------------- k_prep: weight conversion + BN fold + compaction ----------------
// W0t layout: [(br*25 + c)*256 + n]*32 + kk   (bf16), K padded 781->800 (25 chunks of 32)
// Wht layout: [((br*3 + l)*8 + c)*256 + n]*32 + kk (bf16)
// sc/of: (br*4 + layer)*256 + col
__global__ void k_prep(const float* __restrict__ W0, const float* __restrict__ Wh,
                       const float* __restrict__ b0, const float* __restrict__ bh,
                       const float* __restrict__ gm, const float* __restrict__ bt,
                       const float* __restrict__ mn, const float* __restrict__ vr,
                       const int* __restrict__ edx_ij, const int* __restrict__ edx_jk,
                       const int* __restrict__ nei_p,
                       short* __restrict__ W0t, short* __restrict__ Wht,
                       float* __restrict__ sc, float* __restrict__ of,
                       int* __restrict__ lists, int* __restrict__ cnt,
                       int E, int d_in_dim) {
    const int B_W0 = 3200, B_WH = 3072, B_SC = 16;
    int b = blockIdx.x, t = threadIdx.x;
    if (b < B_W0) {
        int idx = b * 256 + t;                 // 819200 elems
        int kk = idx & 31;
        int rest = idx >> 5;
        int n = rest & 255; rest >>= 8;
        int c = rest % 25, br = rest / 25;
        int kidx = c * 32 + kk;
        float v = (kidx < d_in_dim) ? W0[((size_t)br * d_in_dim + kidx) * HCH + n] : 0.f;
        W0t[idx] = f2bs(v);
    } else if (b < B_W0 + B_WH) {
        int idx = (b - B_W0) * 256 + t;        // 786432 elems
        int kk = idx & 31;
        int rest = idx >> 5;
        int n = rest & 255; rest >>= 8;
        int c = rest & 7; rest >>= 3;
        int l = rest % 3, br = rest / 3;
        float v = Wh[((size_t)(br * DEPTH + l) * HCH + (c * 32 + kk)) * HCH + n];
        Wht[idx] = f2bs(v);
    } else if (b < B_W0 + B_WH + B_SC) {
        int idx = (b - B_W0 - B_WH) * 256 + t; // 4096 elems
        int col = idx & 255, l = (idx >> 8) & 3, br = idx >> 10;
        int gi = (br * (DEPTH + 1) + l) * HCH + col;
        float s = gm[gi] * rsqrtf(vr[gi] + EPSBN);
        float bias = (l == 0) ? b0[br * HCH + col] : bh[(br * DEPTH + (l - 1)) * HCH + col];
        sc[idx] = s;
        of[idx] = (bias - mn[gi]) * s + bt[gi];
    } else {
        // wave-aggregated branch compaction (4 atomics per wave)
        int e = (b - (B_W0 + B_WH + B_SC)) * 256 + t;
        int NEI = nei_p[0];
        int lane = t & 63;
        int br = -1;
        if (e < E)
            br = ((edx_ij[e] < NEI) ? 0 : 2) + ((edx_jk[e] < NEI) ? 0 : 1);
        unsigned long long lt = (lane == 63) ? 0x7fffffffffffffffull
                                             : ((1ull << lane) - 1ull);
        #pragma unroll
        for (int bb = 0; bb < 4; ++bb) {
            unsigned long long mk = __ballot(br == bb);
            if (mk) {
                int leader = __ffsll((long long)mk) - 1;
                int base = 0;
                if (lane == leader) base = atomicAdd(&cnt[bb], (int)__popcll(mk));
                base = __shfl(base, leader);
                if (br == bb) {
                    int pos = base + (int)__popcll(mk & lt);
                    lists[(size_t)bb * E + pos] = e;
                }
            }
        }
    }
}

// ---------------- k_main: per-branch 64-edge tile, 4-layer MFMA chain, scatter ----------------
__global__ __launch_bounds__(256)
void k_main(const float* __restrict__ node, const float* __restrict__ geo,
            const int* __restrict__ eidx, const float* __restrict__ att,
            const short* __restrict__ W0t, const short* __restrict__ Wht,
            const float* __restrict__ sc, const float* __restrict__ of,
            const int* __restrict__ lists, const int* __restrict__ cnt,
            float* __restrict__ out, int E) {
    __shared__ __align__(16) short A[64][264];   // bf16 tile, +8 pad -> 2-way bank alias (free)
    __shared__ int s_i[64];
    __shared__ int s_jk[2][64];
    __shared__ int s_e[64];

    int c0 = cnt[0], c1 = cnt[1], c2 = cnt[2], c3 = cnt[3];
    int t0 = (c0 + 63) >> 6, t1 = (c1 + 63) >> 6, t2 = (c2 + 63) >> 6, t3 = (c3 + 63) >> 6;
    int b = blockIdx.x;
    int br, tile, count;
    if (b < t0)                     { br = 0; tile = b;                count = c0; }
    else if (b < t0 + t1)           { br = 1; tile = b - t0;           count = c1; }
    else if (b < t0 + t1 + t2)      { br = 2; tile = b - t0 - t1;      count = c2; }
    else if (b < t0 + t1 + t2 + t3) { br = 3; tile = b - t0 - t1 - t2; count = c3; }
    else return;
    int m = count - tile * 64; if (m > 64) m = 64;

    int t = threadIdx.x;
    if (t < 64) {
        int e = (t < m) ? lists[(size_t)br * E + (size_t)tile * 64 + t] : 0;
        s_e[t] = (t < m) ? e : -1;
        s_i[t] = eidx[e];
        s_jk[0][t] = eidx[E + e];
        s_jk[1][t] = eidx[2 * E + e];
    }
    __syncthreads();

    int wv = t >> 6, lane = t & 63, quad = lane >> 4, l16 = lane & 15;

    floatx4 acc[4][4];
    #pragma unroll
    for (int rt = 0; rt < 4; ++rt)
        #pragma unroll
        for (int ct = 0; ct < 4; ++ct)
            #pragma unroll
            for (int r = 0; r < 4; ++r) acc[rt][ct][r] = 0.f;

    int boff[4];
    #pragma unroll
    for (int ct = 0; ct < 4; ++ct)
        boff[ct] = (wv * 64 + ct * 16 + l16) * 32 + quad * 8;

    // ---------------- layer 0: x = [nf[i] | nf[j] | nf[k] | geo_pad] @ W0 ----------------
    for (int p = 0; p < 4; ++p) {
        __syncthreads();  // previous part's A reads done
        if (p < 3) {
            const int* idxs = (p == 0) ? s_i : s_jk[p - 1];
            #pragma unroll
            for (int it = 0; it < 8; ++it) {
                int job = it * 256 + t;          // 64 rows x 32 chunks of 8 floats
                int row = job >> 5, cc = job & 31;
                const float4* src = reinterpret_cast<const float4*>(
                    node + (size_t)idxs[row] * HCH + cc * 8);
                float4 v0 = src[0], v1 = src[1];
                short8 pk;
                pk[0] = f2bs(v0.x); pk[1] = f2bs(v0.y); pk[2] = f2bs(v0.z); pk[3] = f2bs(v0.w);
                pk[4] = f2bs(v1.x); pk[5] = f2bs(v1.y); pk[6] = f2bs(v1.z); pk[7] = f2bs(v1.w);
                *reinterpret_cast<short8*>(&A[row][cc * 8]) = pk;
            }
        } else {
            if (t < 64) {
                int e = s_e[t];
                #pragma unroll
                for (int kk = 0; kk < 32; ++kk) {
                    float v = (kk < GEO && e >= 0) ? geo[(size_t)e * GEO + kk] : 0.f;
                    A[t][kk] = f2bs(v);
                }
            }
        }
        __syncthreads();

        int nch = (p < 3) ? 8 : 1;
        const short* Wbase = W0t + (size_t)(br * 25 + ((p < 3) ? p * 8 : 24)) * 8192;
        for (int c = 0; c < nch; ++c) {
            short8 af[4];
            #pragma unroll
            for (int rt = 0; rt < 4; ++rt)
                af[rt] = *reinterpret_cast<const short8*>(&A[rt * 16 + l16][c * 32 + quad * 8]);
            const short* Bc = Wbase + (size_t)c * 8192;
            short8 bfr[4];
            #pragma unroll
            for (int ct = 0; ct < 4; ++ct)
                bfr[ct] = *reinterpret_cast<const short8*>(Bc + boff[ct]);
            #pragma unroll
            for (int rt = 0; rt < 4; ++rt)
                #pragma unroll
                for (int ct = 0; ct < 4; ++ct)
                    acc[rt][ct] = __builtin_amdgcn_mfma_f32_16x16x32_bf16(
                        af[rt], bfr[ct], acc[rt][ct], 0, 0, 0);
        }
    }

    // ---------------- BN+relu epilogues, hidden layers, final scatter ----------------
    for (int l = 0; l < 4; ++l) {
        float sv[4], ov[4];
        #pragma unroll
        for (int ct = 0; ct < 4; ++ct) {
            int col = wv * 64 + ct * 16 + l16;
            sv[ct] = sc[(br * 4 + l) * HCH + col];
            ov[ct] = of[(br * 4 + l) * HCH + col];
        }
        if (l < 3) {
            __syncthreads();  // matmul's A reads done before overwrite
            #pragma unroll
            for (int rt = 0; rt < 4; ++rt)
                #pragma unroll
                for (int ct = 0; ct < 4; ++ct) {
                    int col = wv * 64 + ct * 16 + l16;
                    #pragma unroll
                    for (int r = 0; r < 4; ++r) {
                        float h = fmaxf(acc[rt][ct][r] * sv[ct] + ov[ct], 0.f);
                        A[rt * 16 + quad * 4 + r][col] = f2bs(h);
                        acc[rt][ct][r] = 0.f;
                    }
                }
            __syncthreads();
            const short* Wbase = Wht + (size_t)((br * 3 + l) * 8) * 8192;
            for (int c = 0; c < 8; ++c) {
                short8 af[4];
                #pragma unroll
                for (int rt = 0; rt < 4; ++rt)
                    af[rt] = *reinterpret_cast<const short8*>(&A[rt * 16 + l16][c * 32 + quad * 8]);
                const short* Bc = Wbase + (size_t)c * 8192;
                short8 bfr[4];
                #pragma unroll
                for (int ct = 0; ct < 4; ++ct)
                    bfr[ct] = *reinterpret_cast<const short8*>(Bc + boff[ct]);
                #pragma unroll
                for (int rt = 0; rt < 4; ++rt)
                    #pragma unroll
                    for (int ct = 0; ct < 4; ++ct)
                        acc[rt][ct] = __builtin_amdgcn_mfma_f32_16x16x32_bf16(
                            af[rt], bfr[ct], acc[rt][ct], 0, 0, 0);
            }
        } else {
            // final: relu -> leaky_relu (identity on >=0) -> *att -> scatter-add on node i
            float av = att[br];
            #pragma unroll
            for (int rt = 0; rt < 4; ++rt)
                #pragma unroll
                for (int r = 0; r < 4; ++r) {
                    int row = rt * 16 + quad * 4 + r;
                    if (row < m) {
                        float* orow = out + (size_t)s_i[row] * HCH + wv * 64 + l16;
                        #pragma unroll
                        for (int ct = 0; ct < 4; ++ct) {
                            float h = fmaxf(acc[rt][ct][r] * sv[ct] + ov[ct], 0.f);
                            atomicAdd(orow + ct * 16, h * av);
                        }
                    }
                }
        }
    }
}

// ---------------- host launcher ----------------
extern "C" void kernel_launch(void* const* d_in, const int* in_sizes, int n_in,
                              void* d_out, int out_size, void* d_ws, size_t ws_size,
                              hipStream_t stream) {
    const float* node  = (const float*)d_in[0];
    const float* geo   = (const float*)d_in[1];
    const int*   eidx  = (const int*)d_in[2];
    const int*   edxij = (const int*)d_in[3];
    const int*   edxjk = (const int*)d_in[4];
    const float* att   = (const float*)d_in[5];
    const float* W0    = (const float*)d_in[6];
    const float* b0    = (const float*)d_in[7];
    const float* Wh    = (const float*)d_in[8];
    const float* bh    = (const float*)d_in[9];
    const float* gm    = (const float*)d_in[10];
    const float* bt    = (const float*)d_in[11];
    const float* mn    = (const float*)d_in[12];
    const float* vr    = (const float*)d_in[13];
    const int*   neip  = (const int*)d_in[14];

    int E = in_sizes[3];
    int d_in_dim = in_sizes[6] / (4 * HCH);   // 781

    uint8_t* w = (uint8_t*)d_ws;
    size_t sz0 = (size_t)4 * 25 * 256 * 32 * 2;     // W0t bf16
    size_t sz1 = (size_t)4 * 3 * 8 * 256 * 32 * 2;  // Wht bf16
    size_t sz2 = (size_t)4096 * 4;                  // sc
    size_t sz3 = (size_t)4096 * 4;                  // of
    size_t sz4 = (size_t)4 * E * 4;                 // lists
    short* W0t  = (short*)w;
    short* Wht  = (short*)(w + sz0);
    float* sc   = (float*)(w + sz0 + sz1);
    float* of   = (float*)(w + sz0 + sz1 + sz2);
    int*   lists= (int*)(w + sz0 + sz1 + sz2 + sz3);
    int*   cnt  = (int*)(w + sz0 + sz1 + sz2 + sz3 + sz4);

    float* out = (float*)d_out;
    int n4 = out_size / 4;
    k_zero<<<(n4 + 255) / 256, 256, 0, stream>>>((float4*)out, n4, cnt);

    int BCM = (E + 255) / 256;
    k_prep<<<3200 + 3072 + 16 + BCM, 256, 0, stream>>>(
        W0, Wh, b0, bh, gm, bt, mn, vr, edxij, edxjk, neip,
        W0t, Wht, sc, of, lists, cnt, E, d_in_dim);

    int T = (E >> 6) + 8;
    k_main<<<T, 256, 0, stream>>>(node, geo, eidx, att, W0t, Wht,
                                  sc, of, lists, cnt, out, E);
}